// Round 2
// baseline (523.654 us; speedup 1.0000x reference)
//
#include <hip/hip_runtime.h>
#include <math.h>

#define EMB_D 768
#define SEQ_S 512
#define BLOCK 1024
#define NWAVES (BLOCK / 64)            // 16 waves
#define ROWS_PER_WAVE (SEQ_S / NWAVES) // 32 rows per wave
#define RINT 4                         // rows interleaved per iteration

// One block per batch element. Phase 1: each wave computes, for its rows s,
// score[s] = emb[b,s,:]·w_att and t[s] = emb[b,s,:]·w_pred in a single pass
// over the row. RINT=4 rows are processed per iteration so 12 float4 loads
// are in flight before any dependent use, and the 4 shuffle-reduction chains
// interleave (amortizing ds_swizzle latency). Phase 2: block softmax +
// weighted sum + sigmoid -> out[b].
__global__ __launch_bounds__(BLOCK, 4) void attn_pool_kernel(
    const float* __restrict__ emb,     // [B, S, D]
    const float* __restrict__ w_att,   // [D]
    const float* __restrict__ w_pred,  // [D]
    const float* __restrict__ b_pred,  // [1]
    float* __restrict__ out)           // [B]
{
    __shared__ float s_score[SEQ_S];
    __shared__ float s_t[SEQ_S];
    __shared__ float s_red_a[NWAVES];
    __shared__ float s_red_b[NWAVES];

    const int b    = blockIdx.x;
    const int tid  = threadIdx.x;
    const int lane = tid & 63;
    const int wave = tid >> 6;

    // Weight fragments in registers: lane covers float4 indices lane, lane+64, lane+128
    const float4* wa4 = (const float4*)w_att;
    const float4* wp4 = (const float4*)w_pred;
    float4 wa[3], wp[3];
#pragma unroll
    for (int c = 0; c < 3; ++c) {
        wa[c] = wa4[lane + 64 * c];
        wp[c] = wp4[lane + 64 * c];
    }

    const float4* e4 = (const float4*)(emb + (size_t)b * SEQ_S * EMB_D);

    // ---- Phase 1: per-row dual dot products, RINT rows at a time ----
#pragma unroll 1
    for (int r = 0; r < ROWS_PER_WAVE; r += RINT) {
        const int s0 = wave * ROWS_PER_WAVE + r;

        float4 v[RINT][3];
#pragma unroll
        for (int j = 0; j < RINT; ++j) {
            const float4* row = e4 + (size_t)(s0 + j) * (EMB_D / 4);
#pragma unroll
            for (int c = 0; c < 3; ++c)
                v[j][c] = row[lane + 64 * c];
        }

        float sa[RINT], sp[RINT];
#pragma unroll
        for (int j = 0; j < RINT; ++j) {
            sa[j] = 0.f; sp[j] = 0.f;
#pragma unroll
            for (int c = 0; c < 3; ++c) {
                sa[j] = fmaf(v[j][c].x, wa[c].x, sa[j]);
                sa[j] = fmaf(v[j][c].y, wa[c].y, sa[j]);
                sa[j] = fmaf(v[j][c].z, wa[c].z, sa[j]);
                sa[j] = fmaf(v[j][c].w, wa[c].w, sa[j]);
                sp[j] = fmaf(v[j][c].x, wp[c].x, sp[j]);
                sp[j] = fmaf(v[j][c].y, wp[c].y, sp[j]);
                sp[j] = fmaf(v[j][c].z, wp[c].z, sp[j]);
                sp[j] = fmaf(v[j][c].w, wp[c].w, sp[j]);
            }
        }

        // 4 interleaved 64-lane reduction chains (8 values total)
#pragma unroll
        for (int off = 32; off > 0; off >>= 1) {
#pragma unroll
            for (int j = 0; j < RINT; ++j) {
                sa[j] += __shfl_down(sa[j], off, 64);
                sp[j] += __shfl_down(sp[j], off, 64);
            }
        }
        if (lane == 0) {
#pragma unroll
            for (int j = 0; j < RINT; ++j) {
                s_score[s0 + j] = sa[j];
                s_t[s0 + j]     = sp[j];
            }
        }
    }
    __syncthreads();

    // ---- Phase 2: softmax + weighted sum ----
    float score = -INFINITY, tval = 0.f;
    if (tid < SEQ_S) {
        score = s_score[tid];
        tval  = s_t[tid];
    }

    // block max
    float m = score;
#pragma unroll
    for (int off = 1; off < 64; off <<= 1)
        m = fmaxf(m, __shfl_xor(m, off, 64));
    if (lane == 0) s_red_a[wave] = m;
    __syncthreads();
    if (tid == 0) {
        float mm = s_red_a[0];
#pragma unroll
        for (int w = 1; w < NWAVES; ++w) mm = fmaxf(mm, s_red_a[w]);
        s_red_a[0] = mm;
    }
    __syncthreads();
    m = s_red_a[0];
    __syncthreads();   // protect s_red_a before reuse

    float e = (tid < SEQ_S) ? __expf(score - m) : 0.f;
    float se  = e;
    float set = e * tval;
#pragma unroll
    for (int off = 1; off < 64; off <<= 1) {
        se  += __shfl_xor(se, off, 64);
        set += __shfl_xor(set, off, 64);
    }
    if (lane == 0) {
        s_red_a[wave] = se;
        s_red_b[wave] = set;
    }
    __syncthreads();
    if (tid == 0) {
        float Z = 0.f, ET = 0.f;
#pragma unroll
        for (int w = 0; w < NWAVES; ++w) {
            Z  += s_red_a[w];
            ET += s_red_b[w];
        }
        float logit = ET / Z + b_pred[0];
        out[b] = 1.0f / (1.0f + __expf(-logit));
    }
}

extern "C" void kernel_launch(void* const* d_in, const int* in_sizes, int n_in,
                              void* d_out, int out_size, void* d_ws, size_t ws_size,
                              hipStream_t stream) {
    const float* emb    = (const float*)d_in[0]; // [256,512,768]
    const float* w_att  = (const float*)d_in[1]; // [768]
    const float* w_pred = (const float*)d_in[2]; // [768]
    const float* b_pred = (const float*)d_in[3]; // [1]
    float* out = (float*)d_out;                  // [256]

    const int B = in_sizes[0] / (SEQ_S * EMB_D); // 256
    attn_pool_kernel<<<B, BLOCK, 0, stream>>>(emb, w_att, w_pred, b_pred, out);
}

// Round 3
// 520.679 us; speedup vs baseline: 1.0057x; 1.0057x over previous
//
#include <hip/hip_runtime.h>
#include <math.h>

#define EMB_D 768
#define SEQ_S 512
#define NBATCH 256
#define CHUNKS 16                  // chunks per batch
#define CHUNK_ROWS (SEQ_S / CHUNKS) // 32 rows per chunk
#define K1_BLOCK 256               // 4 waves
#define K1_WAVES (K1_BLOCK / 64)
#define ROWS_PER_WAVE (CHUNK_ROWS / K1_WAVES) // 8
#define RINT 4

// K1: grid = B*CHUNKS blocks of 256 threads. Each wave computes
// score[s]=emb[b,s,:]·w_att and t[s]=emb[b,s,:]·w_pred for 8 rows,
// writing to d_ws. Many small blocks -> multiple blocks co-resident per CU,
// dispatch imbalance absorbed (vs. old 1024-thread 1-block/CU layout).
__global__ __launch_bounds__(K1_BLOCK) void score_kernel(
    const float* __restrict__ emb,     // [B, S, D]
    const float* __restrict__ w_att,   // [D]
    const float* __restrict__ w_pred,  // [D]
    float* __restrict__ scores,        // [B, S] (ws)
    float* __restrict__ tvals)         // [B, S] (ws)
{
    const int tid  = threadIdx.x;
    const int lane = tid & 63;
    const int wave = tid >> 6;
    const int b     = blockIdx.x >> 4;      // CHUNKS = 16
    const int chunk = blockIdx.x & 15;

    const float4* wa4 = (const float4*)w_att;
    const float4* wp4 = (const float4*)w_pred;
    float4 wa[3], wp[3];
#pragma unroll
    for (int c = 0; c < 3; ++c) {
        wa[c] = wa4[lane + 64 * c];
        wp[c] = wp4[lane + 64 * c];
    }

    const float4* e4 = (const float4*)(emb + (size_t)b * SEQ_S * EMB_D);
    const int s_base = chunk * CHUNK_ROWS + wave * ROWS_PER_WAVE;

#pragma unroll 1
    for (int r = 0; r < ROWS_PER_WAVE; r += RINT) {
        const int s0 = s_base + r;

        float4 v[RINT][3];
#pragma unroll
        for (int j = 0; j < RINT; ++j) {
            const float4* row = e4 + (size_t)(s0 + j) * (EMB_D / 4);
#pragma unroll
            for (int c = 0; c < 3; ++c)
                v[j][c] = row[lane + 64 * c];
        }

        float sa[RINT], sp[RINT];
#pragma unroll
        for (int j = 0; j < RINT; ++j) {
            sa[j] = 0.f; sp[j] = 0.f;
#pragma unroll
            for (int c = 0; c < 3; ++c) {
                sa[j] = fmaf(v[j][c].x, wa[c].x, sa[j]);
                sa[j] = fmaf(v[j][c].y, wa[c].y, sa[j]);
                sa[j] = fmaf(v[j][c].z, wa[c].z, sa[j]);
                sa[j] = fmaf(v[j][c].w, wa[c].w, sa[j]);
                sp[j] = fmaf(v[j][c].x, wp[c].x, sp[j]);
                sp[j] = fmaf(v[j][c].y, wp[c].y, sp[j]);
                sp[j] = fmaf(v[j][c].z, wp[c].z, sp[j]);
                sp[j] = fmaf(v[j][c].w, wp[c].w, sp[j]);
            }
        }

#pragma unroll
        for (int off = 32; off > 0; off >>= 1) {
#pragma unroll
            for (int j = 0; j < RINT; ++j) {
                sa[j] += __shfl_down(sa[j], off, 64);
                sp[j] += __shfl_down(sp[j], off, 64);
            }
        }
        if (lane == 0) {
#pragma unroll
            for (int j = 0; j < RINT; ++j) {
                scores[b * SEQ_S + s0 + j] = sa[j];
                tvals[b * SEQ_S + s0 + j]  = sp[j];
            }
        }
    }
}

// K2: one block (512 threads = 8 waves) per batch: softmax over scores[b,:],
// weighted sum of t, sigmoid. Reads 4 KB/block — L2/L3-resident.
#define K2_BLOCK 512
#define K2_WAVES (K2_BLOCK / 64)
__global__ __launch_bounds__(K2_BLOCK) void softmax_kernel(
    const float* __restrict__ scores,  // [B, S]
    const float* __restrict__ tvals,   // [B, S]
    const float* __restrict__ b_pred,  // [1]
    float* __restrict__ out)           // [B]
{
    __shared__ float s_red_a[K2_WAVES];
    __shared__ float s_red_b[K2_WAVES];

    const int b    = blockIdx.x;
    const int tid  = threadIdx.x;
    const int lane = tid & 63;
    const int wave = tid >> 6;

    float score = scores[b * SEQ_S + tid];
    float tval  = tvals[b * SEQ_S + tid];

    // block max
    float m = score;
#pragma unroll
    for (int off = 1; off < 64; off <<= 1)
        m = fmaxf(m, __shfl_xor(m, off, 64));
    if (lane == 0) s_red_a[wave] = m;
    __syncthreads();
    if (tid == 0) {
        float mm = s_red_a[0];
#pragma unroll
        for (int w = 1; w < K2_WAVES; ++w) mm = fmaxf(mm, s_red_a[w]);
        s_red_a[0] = mm;
    }
    __syncthreads();
    m = s_red_a[0];
    __syncthreads();

    float e  = __expf(score - m);
    float se = e, set = e * tval;
#pragma unroll
    for (int off = 1; off < 64; off <<= 1) {
        se  += __shfl_xor(se, off, 64);
        set += __shfl_xor(set, off, 64);
    }
    if (lane == 0) {
        s_red_a[wave] = se;
        s_red_b[wave] = set;
    }
    __syncthreads();
    if (tid == 0) {
        float Z = 0.f, ET = 0.f;
#pragma unroll
        for (int w = 0; w < K2_WAVES; ++w) {
            Z  += s_red_a[w];
            ET += s_red_b[w];
        }
        float logit = ET / Z + b_pred[0];
        out[b] = 1.0f / (1.0f + __expf(-logit));
    }
}

extern "C" void kernel_launch(void* const* d_in, const int* in_sizes, int n_in,
                              void* d_out, int out_size, void* d_ws, size_t ws_size,
                              hipStream_t stream) {
    const float* emb    = (const float*)d_in[0]; // [256,512,768]
    const float* w_att  = (const float*)d_in[1]; // [768]
    const float* w_pred = (const float*)d_in[2]; // [768]
    const float* b_pred = (const float*)d_in[3]; // [1]
    float* out = (float*)d_out;                  // [256]

    const int B = in_sizes[0] / (SEQ_S * EMB_D); // 256
    float* scores = (float*)d_ws;                // [B,S]
    float* tvals  = scores + (size_t)B * SEQ_S;  // [B,S]

    score_kernel<<<B * CHUNKS, K1_BLOCK, 0, stream>>>(emb, w_att, w_pred, scores, tvals);
    softmax_kernel<<<B, K2_BLOCK, 0, stream>>>(scores, tvals, b_pred, out);
}